// Round 10
// baseline (5184.616 us; speedup 1.0000x reference)
//
#include <hip/hip_runtime.h>
#include <hip/hip_bf16.h>
#include <math.h>

// LSTM (N=64, T=1024, D=H=512), persistent-kernel bf16-MFMA v4.
//
// ws layout:
//   Wt  bf16 [2048][1024]  @ 0        (4 MB)   [Wx;Wh]^T, col-major-K
//   hb  bf16 [2][64][512]  @ 4MB      (128 KB) h panels (double buffered)
//   flg u32  [256][16]     @ 4MB+128K (16 KB)  per-block flags (word0 = wave0, word8 = wave1)
//
// 256 blocks = 4 row-groups (16 batch rows) x 64 j-groups (8 h-cols x 4 gates).
// 512 thr = 8 waves = (ct = wv&1 col-tile, kq = wv>>1 K-quarter).
// A-fragments loaded DIRECTLY to registers in MFMA layout (no LDS staging):
//   lane (kh=lane>>4, l15=lane&15): row = rowbase+l15, k = kq*128+ks*32+kh*8.
// x_{t+1} prefetched fp32->regs during step t, converted after the barrier.
// Per-wave targeted poll: wave kq polls only its 16 producer blocks.
// ONE __syncthreads per step; part[] double-buffered (max wave skew = 1 step,
// bounded by that barrier: a wave can only start part-write(t+2) after
// s3(t+1), which waits for gate waves to finish reading part[t&1]).

#define TT 1024
#define HH 512
#define FH 2048
#define KK 1024
#define NN 64

typedef __attribute__((ext_vector_type(8))) short bf16x8;
typedef __attribute__((ext_vector_type(4))) float f32x4;
typedef __attribute__((ext_vector_type(4))) int int4v;

__device__ __forceinline__ unsigned short f2bf(float f) {
    return __builtin_bit_cast(unsigned short, __float2bfloat16(f));
}

// ---------------- prep: Wt[col][k] = [Wx;Wh]^T bf16 ----------------
__global__ __launch_bounds__(256)
void prep_wt(const float* __restrict__ Wx, const float* __restrict__ Wh,
             unsigned short* __restrict__ Wt)
{
    __shared__ float tile[64][65];
    const int c0  = blockIdx.x * 64;
    const int k0  = blockIdx.y * 64;
    const int tid = threadIdx.x;

    #pragma unroll
    for (int it = 0; it < 16; ++it) {
        int idx = it * 256 + tid;
        int kk = idx >> 6, cc = idx & 63;
        int k = k0 + kk;
        float w = (k < 512) ? Wx[(size_t)k * FH + c0 + cc]
                            : Wh[(size_t)(k - 512) * FH + c0 + cc];
        tile[kk][cc] = w;
    }
    __syncthreads();

    #pragma unroll
    for (int it = 0; it < 8; ++it) {
        int idx = it * 256 + tid;
        int cc = idx >> 5, kp = idx & 31;
        unsigned int lo = f2bf(tile[kp * 2][cc]);
        unsigned int hi = f2bf(tile[kp * 2 + 1][cc]);
        *(unsigned int*)(Wt + (size_t)(c0 + cc) * KK + k0 + kp * 2) =
            lo | (hi << 16);
    }
}

// ---------------- init: zero flags, seed hb[0] ----------------
__global__ __launch_bounds__(256)
void lstm_init(const float* __restrict__ h0,
               unsigned short* __restrict__ hb,
               unsigned int* __restrict__ flg)
{
    int id = blockIdx.x * 256 + threadIdx.x;
    if (id < 256 * 16) {
        unsigned int* p = flg + id;
        unsigned int z = 0u;
        asm volatile("global_store_dword %0, %1, off sc0 sc1" :: "v"(p), "v"(z) : "memory");
    }
    if (id < NN * HH) {
        unsigned int hv = (unsigned int)f2bf(h0[id]);
        unsigned short* hp = hb + id;
        asm volatile("global_store_short %0, %1, off sc0 sc1" :: "v"(hp), "v"(hv) : "memory");
    }
}

// ---------------- persistent recurrence ----------------
__global__ __launch_bounds__(512)
void lstm_persist(const float* __restrict__ x,
                  const unsigned short* __restrict__ Wt,
                  const float* __restrict__ bias,
                  float* __restrict__ out,
                  unsigned short* __restrict__ hb,
                  unsigned int* __restrict__ flg)
{
    __shared__ float part[2][8][16][20];   // [buf][wave][crow][ccol pad20] 40 KB

    const int tid  = threadIdx.x;
    const int wv   = tid >> 6;
    const int lane = tid & 63;
    const int l15  = lane & 15;
    const int kh   = lane >> 4;            // 0..3

    const int rg = blockIdx.x >> 6;        // row-group 0..3 (rows rg*16..+16)
    const int jg = blockIdx.x & 63;        // j-group 0..63 (cols jg*8..+8)
    const int j0 = jg * 8;
    const int rowbase = rg * 16;

    const int ct = wv & 1;                 // col-tile 0..1
    const int kq = wv >> 1;                // K-quarter 0..3

    const int lc   = ct * 16 + l15;        // local A-col 0..31
    const int gate = lc >> 3;
    const int jj   = lc & 7;
    const int gcol = gate * HH + j0 + jj;

    // ---- hoist B fragments: 4 x-part + 4 h-part (32 VGPR) ----
    const unsigned short* wtp = Wt + (size_t)gcol * KK + kh * 8;
    bf16x8 bx[4], bh[4];
    #pragma unroll
    for (int ks = 0; ks < 4; ++ks) {
        bx[ks] = *(const bf16x8*)(wtp + kq * 128 + ks * 32);
        bh[ks] = *(const bf16x8*)(wtp + 512 + kq * 128 + ks * 32);
    }

    // A-frag global addressing (direct-to-register, MFMA layout)
    const float* xbase = x + (size_t)(rowbase + l15) * TT * 512 + kq * 128 + kh * 8;
    const unsigned short* hlane = hb + (size_t)(rowbase + l15) * HH + kq * 128 + kh * 8;

    // gate-phase ownership (tid < 128 active): waves 0 and 1
    const int grow_l = tid >> 3;           // 0..15 (for tid<128)
    const int q      = tid & 7;
    const int grow   = rowbase + (grow_l & 15);
    const int gj     = j0 + q;
    float bi = 0.f, bf_ = 0.f, bo = 0.f, bg = 0.f;
    if (tid < 128) {
        bi  = bias[gj];
        bf_ = bias[HH + gj];
        bo  = bias[2 * HH + gj];
        bg  = bias[3 * HH + gj];
    }
    float c_reg = 0.f;
    float* outp = out + (size_t)grow * TT * HH + gj;
    unsigned short* hdst0 = hb + (size_t)grow * HH + gj;

    // poll targets: wave kq needs h cols [kq*128, +128) -> producer blocks
    // jg' in [kq*16, kq*16+16), i.e. flags of blocks rg*64 + kq*16 + 0..15.
    const unsigned int* pollp = flg
        + (size_t)(rg * 64 + kq * 16 + (lane & 15)) * 16
        + ((lane >> 4) & 1) * 8;

    unsigned int* myflag = flg + (size_t)blockIdx.x * 16 + ((tid == 64) ? 8 : 0);

    // ---- prologue: load + convert x fragments for t=0 ----
    float4 xpf[8];
    #pragma unroll
    for (int ks = 0; ks < 4; ++ks) {
        xpf[2 * ks]     = *(const float4*)(xbase + ks * 32);
        xpf[2 * ks + 1] = *(const float4*)(xbase + ks * 32 + 4);
    }
    bf16x8 xf[4];
    #pragma unroll
    for (int ks = 0; ks < 4; ++ks) {
        bf16x8 a;
        a[0] = (short)f2bf(xpf[2 * ks].x);     a[1] = (short)f2bf(xpf[2 * ks].y);
        a[2] = (short)f2bf(xpf[2 * ks].z);     a[3] = (short)f2bf(xpf[2 * ks].w);
        a[4] = (short)f2bf(xpf[2 * ks + 1].x); a[5] = (short)f2bf(xpf[2 * ks + 1].y);
        a[6] = (short)f2bf(xpf[2 * ks + 1].z); a[7] = (short)f2bf(xpf[2 * ks + 1].w);
        xf[ks] = a;
    }

    for (int t = 0; t < TT; ++t) {
        const int pb  = t & 1;
        const int cur = t & 1;
        const int nxt = cur ^ 1;

        // ---- poll: wait for this wave's 16 producers to finish step t-1 ----
        if (t > 0) {
            const unsigned int tgt = (unsigned int)t;
            unsigned int v = 0xFFFFFFFFu;
            do {
                if (lane < 32) {
                    asm volatile("global_load_dword %0, %1, off sc0 sc1\n\t"
                                 "s_waitcnt vmcnt(0)"
                                 : "=v"(v) : "v"(pollp) : "memory");
                }
            } while (!__all(v >= tgt));
        }

        // ---- issue h A-frag loads (4 x b128, sc0sc1) ----
        int4v hr[4];
        {
            const unsigned short* hp = hlane + (size_t)cur * NN * HH;
            #pragma unroll
            for (int ks = 0; ks < 4; ++ks) {
                asm volatile("global_load_dwordx4 %0, %1, off sc0 sc1"
                             : "=v"(hr[ks]) : "v"(hp + ks * 32));
            }
        }

        // ---- issue x prefetch for t+1 (8 plain b128, stay in flight) ----
        if (t + 1 < TT) {
            const float* xp = xbase + (size_t)(t + 1) * 512;
            #pragma unroll
            for (int ks = 0; ks < 4; ++ks) {
                xpf[2 * ks]     = *(const float4*)(xp + ks * 32);
                xpf[2 * ks + 1] = *(const float4*)(xp + ks * 32 + 4);
            }
        }

        // ---- x-GEMM: 4 MFMA (fragments already in regs, hides h latency) ----
        f32x4 acc = {0.f, 0.f, 0.f, 0.f};
        #pragma unroll
        for (int ks = 0; ks < 4; ++ks)
            acc = __builtin_amdgcn_mfma_f32_16x16x32_bf16(xf[ks], bx[ks], acc, 0, 0, 0);

        // ---- wait for h loads (keep the 8 newer x loads in flight) ----
        if (t + 1 < TT) {
            asm volatile("s_waitcnt vmcnt(8)" ::: "memory");
        } else {
            asm volatile("s_waitcnt vmcnt(0)" ::: "memory");
        }
        __builtin_amdgcn_sched_barrier(0);   // rule #18: pin MFMA after waitcnt

        // ---- h-GEMM: 4 MFMA ----
        #pragma unroll
        for (int ks = 0; ks < 4; ++ks)
            acc = __builtin_amdgcn_mfma_f32_16x16x32_bf16(
                __builtin_bit_cast(bf16x8, hr[ks]), bh[ks], acc, 0, 0, 0);

        // ---- write partials ----
        #pragma unroll
        for (int rr = 0; rr < 4; ++rr)
            part[pb][wv][kh * 4 + rr][l15] = acc[rr];

        __syncthreads();   // the ONE barrier per step

        // ---- gates (waves 0-1): reduce partials directly, update state ----
        if (tid < 128) {
            float Ai = bi, Af = bf_, Ao = bo, Ag = bg;
            #pragma unroll
            for (int k2 = 0; k2 < 4; ++k2) {
                Ai += part[pb][2 * k2][grow_l][q];
                Af += part[pb][2 * k2][grow_l][q + 8];
                Ao += part[pb][2 * k2 + 1][grow_l][q];
                Ag += part[pb][2 * k2 + 1][grow_l][q + 8];
            }
            float ig = 1.f / (1.f + __expf(-Ai));
            float fg = 1.f / (1.f + __expf(-Af));
            float og = 1.f / (1.f + __expf(-Ao));
            float eg = __expf(2.f * Ag);
            float gg = 1.f - 2.f / (eg + 1.f);          // tanh(Ag)
            c_reg = fg * c_reg + ig * gg;
            float ec = __expf(2.f * c_reg);
            float tc = 1.f - 2.f / (ec + 1.f);          // tanh(c)
            float hn = og * tc;

            // h store -> drain -> flag -> out store (out off critical path)
            unsigned int hv = (unsigned int)f2bf(hn);
            unsigned short* hdst = hdst0 + (size_t)nxt * NN * HH;
            asm volatile("global_store_short %0, %1, off sc0 sc1"
                         :: "v"(hdst), "v"(hv) : "memory");
            asm volatile("s_waitcnt vmcnt(0)" ::: "memory");
            if (t + 1 < TT && (tid == 0 || tid == 64)) {
                unsigned int tgt = (unsigned int)(t + 1);
                asm volatile("global_store_dword %0, %1, off sc0 sc1"
                             :: "v"(myflag), "v"(tgt) : "memory");
            }
            outp[(size_t)t * HH] = hn;
        }

        // ---- convert x prefetch -> fragments for t+1 ----
        if (t + 1 < TT) {
            asm volatile("s_waitcnt vmcnt(0)" ::: "memory");
            #pragma unroll
            for (int ks = 0; ks < 4; ++ks) {
                bf16x8 a;
                a[0] = (short)f2bf(xpf[2 * ks].x);     a[1] = (short)f2bf(xpf[2 * ks].y);
                a[2] = (short)f2bf(xpf[2 * ks].z);     a[3] = (short)f2bf(xpf[2 * ks].w);
                a[4] = (short)f2bf(xpf[2 * ks + 1].x); a[5] = (short)f2bf(xpf[2 * ks + 1].y);
                a[6] = (short)f2bf(xpf[2 * ks + 1].z); a[7] = (short)f2bf(xpf[2 * ks + 1].w);
                xf[ks] = a;
            }
        }
    }
}

extern "C" void kernel_launch(void* const* d_in, const int* in_sizes, int n_in,
                              void* d_out, int out_size, void* d_ws, size_t ws_size,
                              hipStream_t stream)
{
    const float* x  = (const float*)d_in[0];
    const float* h0 = (const float*)d_in[1];
    const float* Wx = (const float*)d_in[2];
    const float* Wh = (const float*)d_in[3];
    const float* b  = (const float*)d_in[4];
    float* out = (float*)d_out;

    char* ws = (char*)d_ws;
    unsigned short* Wt  = (unsigned short*)ws;                                      // 4 MB
    unsigned short* hb  = (unsigned short*)(ws + (size_t)4 * 1024 * 1024);          // 128 KB
    unsigned int*   flg = (unsigned int*)(ws + (size_t)4 * 1024 * 1024 + 131072);   // 16 KB

    prep_wt<<<dim3(32, 16), 256, 0, stream>>>(Wx, Wh, Wt);
    lstm_init<<<128, 256, 0, stream>>>(h0, hb, flg);
    lstm_persist<<<256, 512, 0, stream>>>(x, Wt, b, out, hb, flg);
}